// Round 1
// baseline (564.699 us; speedup 1.0000x reference)
//
#include <hip/hip_runtime.h>
#include <math.h>

#define H 128
#define BASKET 200
#define CHUNKS 8
#define PER (BASKET / CHUNKS)   // 25 items per chunk

__global__ __launch_bounds__(1024)
void gru_encoder_fused(const int* __restrict__ basket,
                       const float* __restrict__ hidden,
                       const float* __restrict__ emb_table,
                       const float* __restrict__ w_ih,
                       const float* __restrict__ w_hh,
                       const float* __restrict__ b_ih,
                       const float* __restrict__ b_hh,
                       float* __restrict__ out)
{
    __shared__ int   s_idx[BASKET];
    __shared__ float s_part[CHUNKS][H];
    __shared__ float s_emb[H];
    __shared__ float s_h[H];
    __shared__ float s_gi[3 * H];
    __shared__ float s_gh[3 * H];

    const int t = threadIdx.x;

    // Phase 0: stage basket indices (scalar-broadcast source for the gather)
    if (t < BASKET) s_idx[t] = basket[t];
    __syncthreads();

    // Phase 1: embedding-bag gather. t = h + 128*c; each chunk c handles 25
    // items; row reads are 512B fully-coalesced; 25 independent loads per
    // thread pipeline the scattered-HBM latency.
    {
        const int h = t & (H - 1);
        const int c = t >> 7;            // 0..7
        float acc = 0.0f;
        #pragma unroll
        for (int i = 0; i < PER; ++i) {
            const int idx = s_idx[c * PER + i];
            acc += emb_table[(size_t)idx * H + h];
        }
        s_part[c][h] = acc;
    }
    __syncthreads();

    // Phase 2: reduce chunk partials, apply the /H average; stage hidden.
    if (t < H) {
        float s = 0.0f;
        #pragma unroll
        for (int c = 0; c < CHUNKS; ++c) s += s_part[c][t];
        s_emb[t] = s * (1.0f / (float)H);
        s_h[t]   = hidden[t];            // hidden[0,0,:]
    }
    __syncthreads();

    // Phase 3: gi = w_ih@emb + b_ih ; gh = w_hh@h + b_hh.
    // 768 rows, one thread each. Split at t=384 (wave boundary 6) so the
    // pointer select is wave-uniform. float4 weight loads; LDS vec reads are
    // same-address broadcasts across the wave (conflict-free).
    if (t < 2 * 3 * H) {
        const bool ih  = (t < 3 * H);
        const int  row = ih ? t : t - 3 * H;
        const float* __restrict__ w   = ih ? w_ih  : w_hh;
        const float* __restrict__ vec = ih ? s_emb : s_h;
        const float4* __restrict__ w4 = (const float4*)(w + (size_t)row * H);
        float acc = ih ? b_ih[row] : b_hh[row];
        #pragma unroll
        for (int k = 0; k < H / 4; ++k) {
            const float4 wv = w4[k];
            acc += wv.x * vec[4 * k + 0]
                 + wv.y * vec[4 * k + 1]
                 + wv.z * vec[4 * k + 2]
                 + wv.w * vec[4 * k + 3];
        }
        if (ih) s_gi[row] = acc; else s_gh[row] = acc;
    }
    __syncthreads();

    // Phase 4: GRU gates + write both tuple outputs (identical).
    if (t < H) {
        const float ir = s_gi[t], iz = s_gi[H + t], inn = s_gi[2 * H + t];
        const float hr = s_gh[t], hz = s_gh[H + t], hnn = s_gh[2 * H + t];
        const float r  = 1.0f / (1.0f + expf(-(ir + hr)));
        const float z  = 1.0f / (1.0f + expf(-(iz + hz)));
        const float n  = tanhf(inn + r * hnn);
        const float hv = s_h[t];
        const float hnew = (1.0f - z) * n + z * hv;
        out[t]     = hnew;
        out[H + t] = hnew;
    }
}

extern "C" void kernel_launch(void* const* d_in, const int* in_sizes, int n_in,
                              void* d_out, int out_size, void* d_ws, size_t ws_size,
                              hipStream_t stream) {
    const int*   basket    = (const int*)  d_in[0];
    const float* hidden    = (const float*)d_in[1];
    const float* emb_table = (const float*)d_in[2];
    const float* w_ih      = (const float*)d_in[3];
    const float* w_hh      = (const float*)d_in[4];
    const float* b_ih      = (const float*)d_in[5];
    const float* b_hh      = (const float*)d_in[6];
    float* out = (float*)d_out;

    gru_encoder_fused<<<1, 1024, 0, stream>>>(basket, hidden, emb_table,
                                              w_ih, w_hh, b_ih, b_hh, out);
}